// Round 5
// baseline (131.468 us; speedup 1.0000x reference)
//
#include <hip/hip_runtime.h>

constexpr int HH = 100;
constexpr int WW = 100;
constexpr int NH = 8;
constexpr int NP = 4;
constexpr int B  = 4;
constexpr int Q  = HH * WW;   // 10000
constexpr int S  = Q;
constexpr int K  = 256;
constexpr int DH = 32;

typedef __attribute__((ext_vector_type(8))) short short8;
typedef __attribute__((ext_vector_type(4))) short short4_v;
typedef __attribute__((ext_vector_type(4))) float f32x4;

struct __align__(8) ushort4_t { unsigned short x, y, z, w; };

__device__ inline unsigned short f2bf(float f) {
    unsigned u = __builtin_bit_cast(unsigned, f);
    u += 0x7fffu + ((u >> 16) & 1u);          // RNE
    return (unsigned short)(u >> 16);
}
__device__ inline float bf2f(unsigned short h) {
    return __builtin_bit_cast(float, ((unsigned)h) << 16);
}
__device__ inline unsigned short f2h(float f) {
    _Float16 h = (_Float16)f;
    return __builtin_bit_cast(unsigned short, h);
}
__device__ inline float h2f(unsigned short u) {
    return (float)__builtin_bit_cast(_Float16, u);
}

// LDS bf16 tile helpers, XOR-swizzled (flips element-index bits 3..5 by row&7)
__device__ inline void lds_st16s(short* base, int row, int stride, int kcol, short8 v) {
    *reinterpret_cast<short8*>(&base[row * stride + (kcol ^ ((row & 7) << 3))]) = v;
}
__device__ inline short8 lds_ld16s(const short* base, int row, int stride, int kcol) {
    return *reinterpret_cast<const short8*>(&base[row * stride + (kcol ^ ((row & 7) << 3))]);
}

__device__ inline short8 cvt8(float4 a, float4 b) {
    short8 r;
    r[0] = (short)f2bf(a.x); r[1] = (short)f2bf(a.y);
    r[2] = (short)f2bf(a.z); r[3] = (short)f2bf(a.w);
    r[4] = (short)f2bf(b.x); r[5] = (short)f2bf(b.y);
    r[6] = (short)f2bf(b.z); r[7] = (short)f2bf(b.w);
    return r;
}

// ---------------------------------------------------------------------------
// Kernel 1: value projection  enc[B*S][256] @ W_val^T + b_val -> vflat bf16
// Tile 32 x 256 (full N), 512 threads, 1250 blocks -> 4 blocks/CU.
// ---------------------------------------------------------------------------
__global__ __launch_bounds__(512) void value_proj(
    const float* __restrict__ enc, const float* __restrict__ Wv,
    const float* __restrict__ bv, unsigned short* __restrict__ vflat)
{
    __shared__ short As[32 * 64];
    __shared__ short Bs[256 * 64];

    const int tid = threadIdx.x;
    const int m0  = blockIdx.x * 32;
    const int lane = tid & 63, w = tid >> 6;
    const int l15 = lane & 15, l4 = lane >> 4;

    const int arow = tid >> 4, ak4 = (tid & 15) * 4;   // A staging: 4 el/thread
    const int brow = tid >> 1, bk32 = (tid & 1) * 32;  // B staging: 32 el/thread

    f32x4 acc[2][2];
#pragma unroll
    for (int i = 0; i < 2; ++i)
#pragma unroll
        for (int j = 0; j < 2; ++j) acc[i][j] = f32x4{0.f, 0.f, 0.f, 0.f};

    for (int k0 = 0; k0 < K; k0 += 64) {
        {
            float4 f = *reinterpret_cast<const float4*>(
                &enc[(size_t)(m0 + arow) * K + k0 + ak4]);
            short4_v s;
            s[0] = (short)f2bf(f.x); s[1] = (short)f2bf(f.y);
            s[2] = (short)f2bf(f.z); s[3] = (short)f2bf(f.w);
            *reinterpret_cast<short4_v*>(&As[arow * 64 + (ak4 ^ ((arow & 7) << 3))]) = s;
        }
        {
            const float* src = &Wv[(size_t)brow * K + k0 + bk32];
#pragma unroll
            for (int c = 0; c < 4; ++c) {
                float4 f0 = *reinterpret_cast<const float4*>(src + c * 8);
                float4 f1 = *reinterpret_cast<const float4*>(src + c * 8 + 4);
                lds_st16s(Bs, brow, 64, bk32 + c * 8, cvt8(f0, f1));
            }
        }
        __syncthreads();
#pragma unroll
        for (int kk = 0; kk < 2; ++kk) {
            const int kc = kk * 32 + l4 * 8;
            short8 a0 = lds_ld16s(As, l15, 64, kc);
            short8 a1 = lds_ld16s(As, 16 + l15, 64, kc);
#pragma unroll
            for (int nf = 0; nf < 2; ++nf) {
                short8 bb = lds_ld16s(Bs, w * 32 + nf * 16 + l15, 64, kc);
                acc[0][nf] = __builtin_amdgcn_mfma_f32_16x16x32_bf16(a0, bb, acc[0][nf], 0, 0, 0);
                acc[1][nf] = __builtin_amdgcn_mfma_f32_16x16x32_bf16(a1, bb, acc[1][nf], 0, 0, 0);
            }
        }
        __syncthreads();
    }

#pragma unroll
    for (int nf = 0; nf < 2; ++nf) {
        const int n = w * 32 + nf * 16 + l15;
        const float bias = bv[n];
        const int h = n >> 5, dd = n & 31;
#pragma unroll
        for (int mf = 0; mf < 2; ++mf) {
#pragma unroll
            for (int r = 0; r < 4; ++r) {
                const int m = m0 + mf * 16 + l4 * 4 + r;
                const int b = m / S, s = m - (m / S) * S;
                vflat[(((size_t)(b * NH + h)) * S + s) * DH + dd] =
                    f2bf(acc[mf][nf][r] + bias);
            }
        }
    }
}

// ---------------------------------------------------------------------------
// Kernel 2: fused {off+attn proj -> softmax+coords -> bilinear gather -> out proj}
// One block per 64 q-rows (m-rows). 512 threads = 8 waves.
// LDS phases (69,632 B total, overlaid):
//   P    [0,12288)      64x96 f16      (phase1 out; As/Bs of phase1 live in tmp region)
//   cidx [12288,20480)  2048 u32       packed corner x/y bytes
//   cw   [20480,36864)  2048 uint2     4x f16 combined weights
//   tmp  [36864,69632)  64x256 bf16    swizzled (phase2b out, phase3 A operand)
//   Ws   [0,32768)      256x64 bf16    phase3 W_out k-slice (over P/cidx/cw, dead)
// ---------------------------------------------------------------------------
__global__ __launch_bounds__(512) void fused_dsa(
    const float* __restrict__ hidden, const float* __restrict__ W_off,
    const float* __restrict__ W_attn, const float* __restrict__ b_off,
    const float* __restrict__ b_attn, const float* __restrict__ ref,
    const unsigned short* __restrict__ vflat, const float* __restrict__ W_out,
    const float* __restrict__ b_out, float* __restrict__ out)
{
    extern __shared__ char smem[];
    unsigned short* P   = (unsigned short*)smem;            // stride 96
    unsigned int*   cidx = (unsigned int*)(smem + 12288);
    uint2*          cw   = (uint2*)(smem + 20480);
    short* tmpB = (short*)(smem + 36864);                   // stride 256
    short* As   = (short*)(smem + 36864);                   // [64][64]
    short* Bs   = (short*)(smem + 45056);                   // [96][64]
    short* Ws   = (short*)smem;                             // [256][64]

    // bijective chunked XCD swizzle (nwg = 625)
    const int nwg = gridDim.x;
    const int q8 = nwg >> 3, r8 = nwg & 7;
    const int xcd = blockIdx.x & 7, pos = blockIdx.x >> 3;
    const int start = (xcd < r8) ? xcd * (q8 + 1) : r8 * (q8 + 1) + (xcd - r8) * q8;
    const int m0 = (start + pos) * 64;

    const int tid = threadIdx.x;
    const int lane = tid & 63, w = tid >> 6;
    const int l15 = lane & 15, l4 = lane >> 4;

    // ---------------- phase 1: P = hidden_tile @ [W_off;W_attn]^T ----------
    const int srow = tid >> 3, sk8 = (tid & 7) * 8;
    const bool bstage2 = (srow < 32);
    const int brow2 = 64 + srow;

    f32x4 acc1[4];
#pragma unroll
    for (int i = 0; i < 4; ++i) acc1[i] = f32x4{0.f, 0.f, 0.f, 0.f};
    const int nb1 = w * 16;

    float4 fa0, fa1, fb00, fb01, fb10, fb11;
    auto ld1 = [&](int k0) {
        const float* s = &hidden[(size_t)(m0 + srow) * K + k0 + sk8];
        fa0 = *reinterpret_cast<const float4*>(s);
        fa1 = *reinterpret_cast<const float4*>(s + 4);
        const float* s0 = &W_off[(size_t)srow * K + k0 + sk8];
        fb00 = *reinterpret_cast<const float4*>(s0);
        fb01 = *reinterpret_cast<const float4*>(s0 + 4);
        if (bstage2) {
            const float* s1 = &W_attn[(size_t)srow * K + k0 + sk8];
            fb10 = *reinterpret_cast<const float4*>(s1);
            fb11 = *reinterpret_cast<const float4*>(s1 + 4);
        }
    };
    auto wr1 = [&]() {
        lds_st16s(As, srow, 64, sk8, cvt8(fa0, fa1));
        lds_st16s(Bs, srow, 64, sk8, cvt8(fb00, fb01));
        if (bstage2) lds_st16s(Bs, brow2, 64, sk8, cvt8(fb10, fb11));
    };

    ld1(0);
    for (int k0 = 0; k0 < K; k0 += 64) {
        wr1();
        __syncthreads();
        if (k0 < K - 64) ld1(k0 + 64);
        if (w < 6) {
#pragma unroll
            for (int kk = 0; kk < 2; ++kk) {
                const int kc = kk * 32 + l4 * 8;
                short8 a[4];
#pragma unroll
                for (int mf = 0; mf < 4; ++mf)
                    a[mf] = lds_ld16s(As, mf * 16 + l15, 64, kc);
                short8 bb = lds_ld16s(Bs, nb1 + l15, 64, kc);
#pragma unroll
                for (int mf = 0; mf < 4; ++mf)
                    acc1[mf] = __builtin_amdgcn_mfma_f32_16x16x32_bf16(a[mf], bb, acc1[mf], 0, 0, 0);
            }
        }
        __syncthreads();
    }
    if (w < 6) {
        const int col = nb1 + l15;
        const float bias = (col < 64) ? b_off[col] : b_attn[col - 64];
#pragma unroll
        for (int mf = 0; mf < 4; ++mf)
#pragma unroll
            for (int r = 0; r < 4; ++r) {
                const int row = mf * 16 + l4 * 4 + r;
                P[row * 96 + col] = f2h(acc1[mf][r] + bias);
            }
    }
    __syncthreads();

    // ---------------- phase 2a: softmax + corner coords/weights ------------
    {
        const int r = tid >> 3, h = tid & 7;
        const int m = m0 + r;
        const float refx = ref[(size_t)m * 2 + 0];
        const float refy = ref[(size_t)m * 2 + 1];
        float l[NP];
#pragma unroll
        for (int p = 0; p < NP; ++p) l[p] = h2f(P[r * 96 + 64 + h * 4 + p]);
        const float mx = fmaxf(fmaxf(l[0], l[1]), fmaxf(l[2], l[3]));
        float e[NP]; float esum = 0.f;
#pragma unroll
        for (int p = 0; p < NP; ++p) { e[p] = __expf(l[p] - mx); esum += e[p]; }
        const float inv = 1.f / esum;
#pragma unroll
        for (int p = 0; p < NP; ++p) {
            const float ox = h2f(P[r * 96 + h * 8 + p * 2 + 0]);
            const float oy = h2f(P[r * 96 + h * 8 + p * 2 + 1]);
            const float x = fmaf(refx, (float)WW, ox) - 0.5f;
            const float y = fmaf(refy, (float)HH, oy) - 0.5f;
            const float x0f = floorf(x), y0f = floorf(y);
            const float wx1 = x - x0f, wx0 = 1.f - wx1;
            const float wy1 = y - y0f, wy0 = 1.f - wy1;
            const int x0 = (int)x0f, y0 = (int)y0f;
            const bool vx0 = (x0 >= 0) && (x0 < WW);
            const bool vx1 = (x0 + 1 >= 0) && (x0 + 1 < WW);
            const bool vy0 = (y0 >= 0) && (y0 < HH);
            const bool vy1 = (y0 + 1 >= 0) && (y0 + 1 < HH);
            const int xi0 = min(max(x0, 0), WW - 1);
            const int xi1 = min(max(x0 + 1, 0), WW - 1);
            const int yi0 = min(max(y0, 0), HH - 1);
            const int yi1 = min(max(y0 + 1, 0), HH - 1);
            const float ap = e[p] * inv;
            const float c0 = ap * wx0 * wy0 * ((vx0 && vy0) ? 1.f : 0.f);
            const float c1 = ap * wx1 * wy0 * ((vx1 && vy0) ? 1.f : 0.f);
            const float c2 = ap * wx0 * wy1 * ((vx0 && vy1) ? 1.f : 0.f);
            const float c3 = ap * wx1 * wy1 * ((vx1 && vy1) ? 1.f : 0.f);
            const int trip = ((r * 8 + h) << 2) + p;
            cidx[trip] = (unsigned)xi0 | ((unsigned)xi1 << 8)
                       | ((unsigned)yi0 << 16) | ((unsigned)yi1 << 24);
            uint2 wv;
            wv.x = (unsigned)f2h(c0) | ((unsigned)f2h(c1) << 16);
            wv.y = (unsigned)f2h(c2) | ((unsigned)f2h(c3) << 16);
            cw[trip] = wv;
        }
    }
    __syncthreads();

    // ---------------- phase 2b: gather + accumulate -> tmp -----------------
    {
        const int r = tid >> 3, d0 = (tid & 7) * 4;
        const int m = m0 + r;
        const int b = m / Q;
        float o[8][4];
#pragma unroll
        for (int h = 0; h < 8; ++h)
#pragma unroll
            for (int c = 0; c < 4; ++c) o[h][c] = 0.f;

#pragma unroll
        for (int h = 0; h < 8; ++h) {
            const unsigned short* vb = vflat + (size_t)(b * NH + h) * (S * DH);
#pragma unroll
            for (int p = 0; p < NP; ++p) {
                const int trip = ((r * 8 + h) << 2) + p;
                const unsigned u = cidx[trip];
                const uint2 wv = cw[trip];
                const int xi0 = u & 255, xi1 = (u >> 8) & 255;
                const int yi0 = (u >> 16) & 255, yi1 = u >> 24;
                const float c0 = h2f((unsigned short)(wv.x & 0xffff));
                const float c1 = h2f((unsigned short)(wv.x >> 16));
                const float c2 = h2f((unsigned short)(wv.y & 0xffff));
                const float c3 = h2f((unsigned short)(wv.y >> 16));
                const ushort4_t v0 = *reinterpret_cast<const ushort4_t*>(&vb[(size_t)((yi0 * WW + xi0) * DH + d0)]);
                const ushort4_t v1 = *reinterpret_cast<const ushort4_t*>(&vb[(size_t)((yi0 * WW + xi1) * DH + d0)]);
                const ushort4_t v2 = *reinterpret_cast<const ushort4_t*>(&vb[(size_t)((yi1 * WW + xi0) * DH + d0)]);
                const ushort4_t v3 = *reinterpret_cast<const ushort4_t*>(&vb[(size_t)((yi1 * WW + xi1) * DH + d0)]);
                o[h][0] = fmaf(c0, bf2f(v0.x), fmaf(c1, bf2f(v1.x), fmaf(c2, bf2f(v2.x), fmaf(c3, bf2f(v3.x), o[h][0]))));
                o[h][1] = fmaf(c0, bf2f(v0.y), fmaf(c1, bf2f(v1.y), fmaf(c2, bf2f(v2.y), fmaf(c3, bf2f(v3.y), o[h][1]))));
                o[h][2] = fmaf(c0, bf2f(v0.z), fmaf(c1, bf2f(v1.z), fmaf(c2, bf2f(v2.z), fmaf(c3, bf2f(v3.z), o[h][2]))));
                o[h][3] = fmaf(c0, bf2f(v0.w), fmaf(c1, bf2f(v1.w), fmaf(c2, bf2f(v2.w), fmaf(c3, bf2f(v3.w), o[h][3]))));
            }
        }
#pragma unroll
        for (int h = 0; h < 8; ++h) {
            const int c = h * 32 + d0;
            const int idx = r * 256 + (c ^ ((r & 7) << 3));
            ushort4_t ov;
            ov.x = f2bf(o[h][0]); ov.y = f2bf(o[h][1]);
            ov.z = f2bf(o[h][2]); ov.w = f2bf(o[h][3]);
            *reinterpret_cast<ushort4_t*>(&tmpB[idx]) = ov;
        }
    }
    __syncthreads();

    // ---------------- phase 3: out = tmp @ W_out^T + b_out -----------------
    f32x4 acc2[4][2];
#pragma unroll
    for (int i = 0; i < 4; ++i)
#pragma unroll
        for (int j = 0; j < 2; ++j) acc2[i][j] = f32x4{0.f, 0.f, 0.f, 0.f};

    const int wrow = tid >> 1, wk32 = (tid & 1) * 32;
    const int nb3 = w * 32;

    for (int k0 = 0; k0 < K; k0 += 64) {
        {
            const float* s = &W_out[(size_t)wrow * K + k0 + wk32];
#pragma unroll
            for (int c = 0; c < 4; ++c) {
                float4 f0 = *reinterpret_cast<const float4*>(s + c * 8);
                float4 f1 = *reinterpret_cast<const float4*>(s + c * 8 + 4);
                lds_st16s(Ws, wrow, 64, wk32 + c * 8, cvt8(f0, f1));
            }
        }
        __syncthreads();
#pragma unroll
        for (int kk = 0; kk < 2; ++kk) {
            const int kc = kk * 32 + l4 * 8;
            short8 a[4];
#pragma unroll
            for (int mf = 0; mf < 4; ++mf)
                a[mf] = lds_ld16s(tmpB, mf * 16 + l15, 256, k0 + kc);
#pragma unroll
            for (int nf = 0; nf < 2; ++nf) {
                short8 bb = lds_ld16s(Ws, nb3 + nf * 16 + l15, 64, kc);
#pragma unroll
                for (int mf = 0; mf < 4; ++mf)
                    acc2[mf][nf] = __builtin_amdgcn_mfma_f32_16x16x32_bf16(a[mf], bb, acc2[mf][nf], 0, 0, 0);
            }
        }
        __syncthreads();
    }

#pragma unroll
    for (int nf = 0; nf < 2; ++nf) {
        const int n = nb3 + nf * 16 + l15;
        const float bias = b_out[n];
#pragma unroll
        for (int mf = 0; mf < 4; ++mf)
#pragma unroll
            for (int r = 0; r < 4; ++r) {
                const int mrow = m0 + mf * 16 + l4 * 4 + r;
                out[(size_t)mrow * K + n] = acc2[mf][nf][r] + bias;
            }
    }
}

// ---------------------------------------------------------------------------
extern "C" void kernel_launch(void* const* d_in, const int* in_sizes, int n_in,
                              void* d_out, int out_size, void* d_ws, size_t ws_size,
                              hipStream_t stream)
{
    const float* hidden = (const float*)d_in[0];
    const float* enc    = (const float*)d_in[1];
    const float* refp   = (const float*)d_in[2];
    const float* W_off  = (const float*)d_in[4];
    const float* b_off  = (const float*)d_in[5];
    const float* W_attn = (const float*)d_in[6];
    const float* b_attn = (const float*)d_in[7];
    const float* W_val  = (const float*)d_in[8];
    const float* b_val  = (const float*)d_in[9];
    const float* W_out  = (const float*)d_in[10];
    const float* b_out  = (const float*)d_in[11];
    float* out = (float*)d_out;

    unsigned short* vflat = (unsigned short*)d_ws;   // B*NH*S*DH bf16 = 20.5 MB

    const int M = B * Q;  // 40000

    // 1) value projection -> vflat bf16 [B*NH][S][32]
    value_proj<<<M / 32, 512, 0, stream>>>(enc, W_val, b_val, vflat);

    // 2) fused proj + sampling + out-projection
    fused_dsa<<<M / 64, 512, 69632, stream>>>(
        hidden, W_off, W_attn, b_off, b_attn, refp, vflat, W_out, b_out, out);
}